// Round 1
// 282.566 us; speedup vs baseline: 1.0203x; 1.0203x over previous
//
#include <hip/hip_runtime.h>
#include <math.h>

static constexpr float kL1   = 0.5f;
static constexpr float kL2   = 1.5f;
static constexpr float kBeta = 50000000.0f;
static constexpr float kEps  = 1e-08f;

__device__ __forceinline__ float waveSum(float v) {
#pragma unroll
    for (int off = 32; off > 0; off >>= 1) v += __shfl_xor(v, off, 64);
    return v;
}

__device__ __forceinline__ float tubeTail(float dot, float pp, float gg) {
    float p_norm = sqrtf(pp);
    float g_norm = sqrtf(gg);
    float denom  = p_norm * g_norm;
    float cosine = (denom == 0.0f) ? 0.0f : dot / denom;
    float s_s    = 1.0f - cosine * cosine;
    float sine   = (s_s < 0.0f) ? 0.0f : sqrtf((s_s <= 0.0f) ? kEps : s_s);
    float gd     = (g_norm == 0.0f) ? (g_norm + kEps) : g_norm;
    float pc     = p_norm * cosine;
    float r_all  = pc / gd;
    float base   = p_norm * sine + fabsf(g_norm - pc);
    float ds     = (r_all >= 1.0f) ? (kL1 * base)
                 : ((r_all >= 0.0f) ? base
                                    : kL2 * fabsf(pc - g_norm - p_norm * sine));
    // -log(tanh(t)) = log(1+e^{-2t}) - log(1-e^{-2t})
    float t  = 1.0f / ds;
    float em = __expf(-2.0f * t);
    return __logf(1.0f + em) - __logf(fmaxf(1.0f - em, 1e-30f));
}

#define ACC3(A, L)                                        \
    dot += A.x*L.x + A.y*L.y + A.z*L.z + A.w*L.w;         \
    pp  += A.x*A.x + A.y*A.y + A.z*A.z + A.w*A.w;         \
    gg  += L.x*L.x + L.y*L.y + L.z*L.z + L.w*L.w;

__global__ __launch_bounds__(256, 4) void fused_loss_partials(
    const float* __restrict__ fusion_out, const float* __restrict__ comple_out,
    const float* __restrict__ labels,     const float* __restrict__ labels_enc,
    const float* __restrict__ xA,  const float* __restrict__ xAr,
    const float* __restrict__ xB,  const float* __restrict__ xBr,
    const float* __restrict__ xC,  const float* __restrict__ xCr,
    const float* __restrict__ mu,  const float* __restrict__ logvar,
    float* __restrict__ partials,
    int B, int C, int Z)
{
    const int lane = threadIdx.x & 63;
    const int wave = threadIdx.x >> 6;
    const int wavesPerBlock = blockDim.x >> 6;
    const int globalWave = blockIdx.x * wavesPerBlock + wave;
    const int totalWaves = gridDim.x * wavesPerBlock;         // 8192
    const int D = 512;                                        // compile-time

    float my = 0.0f;

    // ================= TUBE: half-wave per row, 2 rows/iter, prefetched =================
    // Rows laid out flat: [xAr|xBr|xCr|comple_out] vs [xA|xB|xC|labels_enc], 4*B rows.
    // Pair index t covers rows (2t, 2t+1) — always within one tensor (B even).
    {
        const int h   = lane >> 5;     // which row of the pair this half-wave owns
        const int sub = lane & 31;
        const int NP  = (4 * B) >> 1;  // 32768 pairs
        const int fo  = h * 128 + sub; // float4 offset: row h, lanes cover 32 float4/load

        float tubeAcc = 0.0f;

        int t = globalWave;
        float4 cA0, cA1, cA2, cA3, cL0, cL1, cL2, cL3;
        if (t < NP) {
            const int row0 = 2 * t;
            const int p = row0 >> 14, r0 = row0 & (B - 1);
            const float* ab = (p == 0) ? xAr : (p == 1) ? xBr : (p == 2) ? xCr : comple_out;
            const float* lb = (p == 0) ? xA  : (p == 1) ? xB  : (p == 2) ? xC  : labels_enc;
            const float4* a = (const float4*)(ab + (size_t)r0 * D) + fo;
            const float4* l = (const float4*)(lb + (size_t)r0 * D) + fo;
            cA0 = a[0]; cA1 = a[32]; cA2 = a[64]; cA3 = a[96];
            cL0 = l[0]; cL1 = l[32]; cL2 = l[64]; cL3 = l[96];
        }
        for (; t < NP; t += totalWaves) {
            // ---- issue next pair's loads BEFORE reducing current (keeps 8KB in flight) ----
            int tn = t + totalWaves;
            if (tn >= NP) tn = t;                 // clamped dummy prefetch on last iter
            const int rown = 2 * tn;
            const int pn = rown >> 14, rn = rown & (B - 1);
            const float* abn = (pn == 0) ? xAr : (pn == 1) ? xBr : (pn == 2) ? xCr : comple_out;
            const float* lbn = (pn == 0) ? xA  : (pn == 1) ? xB  : (pn == 2) ? xC  : labels_enc;
            const float4* an = (const float4*)(abn + (size_t)rn * D) + fo;
            const float4* ln = (const float4*)(lbn + (size_t)rn * D) + fo;
            float4 nA0 = an[0], nA1 = an[32], nA2 = an[64], nA3 = an[96];
            float4 nL0 = ln[0], nL1 = ln[32], nL2 = ln[64], nL3 = ln[96];

            // ---- per-lane partials for this half-wave's row ----
            float dot = 0.0f, pp = 0.0f, gg = 0.0f;
            ACC3(cA0, cL0); ACC3(cA1, cL1); ACC3(cA2, cL2); ACC3(cA3, cL3);

            // ---- 5-step butterfly within each 32-lane half (3 chains, not 6) ----
#pragma unroll
            for (int off = 16; off > 0; off >>= 1) {
                dot += __shfl_xor(dot, off, 64);
                pp  += __shfl_xor(pp,  off, 64);
                gg  += __shfl_xor(gg,  off, 64);
            }

            // ---- tail: both rows in parallel on the two halves, zero divergence ----
            tubeAcc += tubeTail(dot, pp, gg);

            cA0 = nA0; cA1 = nA1; cA2 = nA2; cA3 = nA3;
            cL0 = nL0; cL1 = nL1; cL2 = nL2; cL3 = nL3;
        }
        // each row's tail is replicated on 32 lanes -> scale by 1/32; mean over B
        my += tubeAcc * (1.0f / (32.0f * (float)B));
    }

    // ================= KL over mu/logvar (pure streaming, 1 float4/thread) =================
    {
        const int n4 = (B * Z) >> 2;
        const float4* mu4 = (const float4*)mu;
        const float4* lv4 = (const float4*)logvar;
        const int tid      = blockIdx.x * blockDim.x + threadIdx.x;
        const int nThreads = gridDim.x * blockDim.x;
        float acc = 0.0f;
        for (int i = tid; i < n4; i += nThreads) {
            float4 m = mu4[i];
            float4 l = lv4[i];
            acc += (1.0f + l.x - m.x * m.x - __expf(l.x));
            acc += (1.0f + l.y - m.y * m.y - __expf(l.y));
            acc += (1.0f + l.z - m.z * m.z - __expf(l.z));
            acc += (1.0f + l.w - m.w * m.w - __expf(l.w));
        }
        my += acc * (-0.5f * kBeta / (float)(B * Z));
    }

    // ================= Cross-entropy: one wave per row over C=100 =================
    {
        float acc = 0.0f;
        for (int r = globalWave; r < B; r += totalWaves) {
            const float* lrow = labels     + (size_t)r * C;
            const float* frow = fusion_out + (size_t)r * C;
            const bool has0 = (lane < C);
            const bool has1 = (lane + 64 < C);
            float v0 = has0 ? lrow[lane]      : -INFINITY;
            float v1 = has1 ? lrow[lane + 64] : -INFINITY;
            float f0 = has0 ? frow[lane]      : -INFINITY;
            float f1 = has1 ? frow[lane + 64] : -INFINITY;
            float bv; int bi;
            if (v1 > v0) { bv = v1; bi = lane + 64; } else { bv = v0; bi = lane; }
#pragma unroll
            for (int off = 32; off > 0; off >>= 1) {
                float ov = __shfl_xor(bv, off, 64);
                int   oi = __shfl_xor(bi, off, 64);
                if (ov > bv || (ov == bv && oi < bi)) { bv = ov; bi = oi; }
            }
            float m = fmaxf(f0, f1);
#pragma unroll
            for (int off = 32; off > 0; off >>= 1) m = fmaxf(m, __shfl_xor(m, off, 64));
            float e = 0.0f;
            if (has0) e += __expf(f0 - m);
            if (has1) e += __expf(f1 - m);
            e = waveSum(e);
            float tgt = (bi < 64) ? __shfl(f0, bi, 64) : __shfl(f1, bi - 64, 64);
            if (lane == 0) acc += -(tgt - m - __logf(e));
        }
        my += acc / (float)B;
    }

    // ================= block reduce -> per-block partial (NO atomics) =================
    float s = waveSum(my);
    __shared__ float sw[8];
    if (lane == 0) sw[wave] = s;
    __syncthreads();
    if (threadIdx.x == 0) {
        float tot = 0.0f;
        for (int i = 0; i < wavesPerBlock; ++i) tot += sw[i];
        partials[blockIdx.x] = tot;
    }
}

__global__ __launch_bounds__(256) void reduce_partials(
    const float* __restrict__ partials, float* __restrict__ out, int n)
{
    float s = 0.0f;
    for (int i = threadIdx.x; i < n; i += 256) s += partials[i];
    s = waveSum(s);
    __shared__ float sw[4];
    const int lane = threadIdx.x & 63;
    const int wave = threadIdx.x >> 6;
    if (lane == 0) sw[wave] = s;
    __syncthreads();
    if (threadIdx.x == 0) out[0] = sw[0] + sw[1] + sw[2] + sw[3];
}

extern "C" void kernel_launch(void* const* d_in, const int* in_sizes, int n_in,
                              void* d_out, int out_size, void* d_ws, size_t ws_size,
                              hipStream_t stream) {
    const float* fusion_out = (const float*)d_in[0];
    const float* comple_out = (const float*)d_in[1];
    const float* labels     = (const float*)d_in[2];
    const float* labels_enc = (const float*)d_in[3];
    const float* xA  = (const float*)d_in[4];
    const float* xAr = (const float*)d_in[5];
    const float* xB  = (const float*)d_in[6];
    const float* xBr = (const float*)d_in[7];
    const float* xC  = (const float*)d_in[8];
    const float* xCr = (const float*)d_in[9];
    const float* mu  = (const float*)d_in[10];
    const float* lv  = (const float*)d_in[11];
    float* out = (float*)d_out;
    float* ws  = (float*)d_ws;

    const int B = 16384;
    const int C = in_sizes[0] / B;    // 100
    const int Z = in_sizes[10] / B;   // 128

    const int totalBlocks = 2048;     // uniform persistent blocks: every block does
                                      // a tube slice + KL slice + CE slice

    fused_loss_partials<<<totalBlocks, 256, 0, stream>>>(
        fusion_out, comple_out, labels, labels_enc,
        xA, xAr, xB, xBr, xC, xCr, mu, lv,
        ws, B, C, Z);
    reduce_partials<<<1, 256, 0, stream>>>(ws, out, totalBlocks);
}